// Round 21
// baseline (28.850 us; speedup 1.0000x reference)
//
#include <hip/hip_runtime.h>
#include <hip/hip_bf16.h>
#include <math.h>

#define N_NODES 2048
#define FIN 128
#define FOUT 64
#define BS 8
#define ALPHA 0.2f
#define LOG2E 1.4426950408889634f

typedef __attribute__((ext_vector_type(8))) short short8v;
typedef __attribute__((ext_vector_type(4))) float f32x4;

__device__ __forceinline__ unsigned int pack2bf(float a, float b) {
  __hip_bfloat162 t = __float22bfloat162_rn(make_float2(a, b));
  unsigned int r;
  __builtin_memcpy(&r, &t, 4);
  return r;
}
// hi/lo bf16 split of a float pair via packed cvt (RNE)
__device__ __forceinline__ void split2(float f0, float f1, unsigned &hi, unsigned &lo) {
  hi = pack2bf(f0, f1);
  const float h0 = __uint_as_float(hi << 16);
  const float h1 = __uint_as_float(hi & 0xFFFF0000u);
  lo = pack2bf(f0 - h0, f1 - h1);
}
__device__ __forceinline__ float elu_f(float v) {
  return v > 0.f ? v : expm1f(v);
}

// ---------------- gat_prep: 8-row blocks for 2x memory concurrency -----------
// 2048 blocks x 256 threads (4 waves), 6 blocks/CU target (24 waves/CU).
// Block bx: br=bx>>1 (16-row tile), hh=bx&1 (8-row half). MFMA computes a
// 16-row tile with rows 8..15 duplicated (free); only rows 0..7 stored.
// Mask: block bx packs adjacency row bx (bijective).
__global__ __launch_bounds__(256, 6) void gat_prep(const float* __restrict__ x,
                                                   const int* __restrict__ adj,
                                                   const float* __restrict__ W,
                                                   const float* __restrict__ a,
                                                   short* __restrict__ hp,
                                                   float* __restrict__ e1g,
                                                   float* __restrict__ f1g,
                                                   float* __restrict__ e2g,
                                                   float* __restrict__ f2g,
                                                   unsigned int* __restrict__ mask32) {
  const int bx = blockIdx.x;            // 0..2047
  const int br = bx >> 1;               // 16-row tile id
  const int hh = bx & 1;                // which 8-row half
  const int b = br >> 7;
  const int t16 = br & 127;
  const int i0 = t16 * 16 + hh * 8;     // first of this block's 8 rows
  const int t = threadIdx.x;
  const int w = t >> 6, lane = t & 63;
  const int kg = lane >> 4, rl = lane & 15;

  __shared__ float x_lds[8][132];            // 4.2 KB
  __shared__ float h_lds[8][68];             // 2.2 KB
  __shared__ unsigned char nib[512];         // 0.5 KB

  // ---- adj: one row (= bx); wave w covers cols w*512..+511 (2 int4 loads) ----
  {
    const int4* ar = reinterpret_cast<const int4*>(
        adj + (long long)bx * N_NODES + w * 512);
    #pragma unroll
    for (int c = 0; c < 2; ++c) {
      const int4 v = ar[c * 64 + lane];
      const unsigned n = (v.x > 0 ? 1u : 0u) | (v.y > 0 ? 2u : 0u) |
                         (v.z > 0 ? 4u : 0u) | (v.w > 0 ? 8u : 0u);
      nib[w * 128 + c * 64 + lane] = (unsigned char)n;
    }
  }

  // ---- coop x stage: 8 rows x 128 cols; thread t -> row t>>5, col (t&31)*4 ----
  {
    const float* xrow = x + ((long long)b * N_NODES + i0 + (t >> 5)) * FIN + (t & 31) * 4;
    *reinterpret_cast<float4*>(&x_lds[t >> 5][(t & 31) * 4]) =
        *reinterpret_cast<const float4*>(xrow);
  }

  // ---- W fragments (hi/lo) inline for this wave's ct = w ----
  union u8s { short8v v; unsigned u[4]; };
  u8s bh[4], bl[4];
  #pragma unroll
  for (int ks = 0; ks < 4; ++ks) {
    #pragma unroll
    for (int pe = 0; pe < 4; ++pe) {
      const float w0 = W[(ks * 32 + kg * 8 + 2 * pe) * FOUT + w * 16 + rl];
      const float w1 = W[(ks * 32 + kg * 8 + 2 * pe + 1) * FOUT + w * 16 + rl];
      split2(w0, w1, bh[ks].u[pe], bl[ks].u[pe]);
    }
  }

  __syncthreads();   // x_lds + nib ready

  // ---- h tile via 3-term MFMA; A rows 8..15 duplicate rows 0..7 ----
  f32x4 ahh = {0.f, 0.f, 0.f, 0.f};
  f32x4 ahl = {0.f, 0.f, 0.f, 0.f};
  f32x4 alh = {0.f, 0.f, 0.f, 0.f};
  #pragma unroll
  for (int ks = 0; ks < 4; ++ks) {
    const float4 xa = *reinterpret_cast<const float4*>(&x_lds[rl & 7][ks * 32 + kg * 8]);
    const float4 xb = *reinterpret_cast<const float4*>(&x_lds[rl & 7][ks * 32 + kg * 8 + 4]);
    const float xf[8] = {xa.x, xa.y, xa.z, xa.w, xb.x, xb.y, xb.z, xb.w};
    u8s xh, xl;
    #pragma unroll
    for (int pe = 0; pe < 4; ++pe)
      split2(xf[2 * pe], xf[2 * pe + 1], xh.u[pe], xl.u[pe]);
    ahh = __builtin_amdgcn_mfma_f32_16x16x32_bf16(xh.v, bh[ks].v, ahh, 0, 0, 0);
    ahl = __builtin_amdgcn_mfma_f32_16x16x32_bf16(xh.v, bl[ks].v, ahl, 0, 0, 0);
    alh = __builtin_amdgcn_mfma_f32_16x16x32_bf16(xl.v, bh[ks].v, alh, 0, 0, 0);
  }
  const f32x4 acc = (ahh + ahl) + alh;
  // C/D row = kg*4+r, col = w*16+rl; only rows 0..7 (kg<2) are real
  if (kg < 2) {
    #pragma unroll
    for (int r = 0; r < 4; ++r)
      h_lds[kg * 4 + r][w * 16 + rl] = acc[r];
  }

  // ---- mask word assembly: threads 0..63 -> word t of row bx ----
  if (t < 64) {
    uint2 bytes;
    __builtin_memcpy(&bytes, &nib[t * 8], 8);
    const unsigned x0 = bytes.x, x1 = bytes.y;
    const unsigned lo16 = (x0 & 0xFu) | ((x0 >> 4) & 0xF0u) |
                          ((x0 >> 8) & 0xF00u) | ((x0 >> 12) & 0xF000u);
    const unsigned hi16 = (x1 & 0xFu) | ((x1 >> 4) & 0xF0u) |
                          ((x1 >> 8) & 0xF00u) | ((x1 >> 12) & 0xF000u);
    mask32[bx * 64 + t] = lo16 | (hi16 << 16);
  }

  __syncthreads();   // h_lds ready

  // ---- s1/s2 reductions -> exp-factor tables (2 rows per wave) ----
  {
    const float a1v = a[lane], a2v = a[FOUT + lane];
    #pragma unroll
    for (int rr = 0; rr < 2; ++rr) {
      const float hv = h_lds[2 * w + rr][lane];
      float p = hv * a1v, q = hv * a2v;
      #pragma unroll
      for (int off = 32; off > 0; off >>= 1) {
        p += __shfl_xor(p, off);
        q += __shfl_xor(q, off);
      }
      if (lane == 0) {
        const long long idx = (long long)b * N_NODES + i0 + 2 * w + rr;
        const float pl = p * LOG2E, ql = q * LOG2E;
        e1g[idx] = __builtin_amdgcn_exp2f(pl);
        f1g[idx] = __builtin_amdgcn_exp2f(pl * ALPHA);
        e2g[idx] = __builtin_amdgcn_exp2f(ql);
        f2g[idx] = __builtin_amdgcn_exp2f(ql * ALPHA);
      }
    }
  }

  // ---- hp pack: wave w = ct; this 8-row block is k-group q of hp tile jt ----
  if (lane < 16) {
    const int jt = t16 >> 1;
    const int q = (t16 & 1) * 2 + hh;
    u8s o;
    #pragma unroll
    for (int i = 0; i < 4; ++i)
      o.u[i] = pack2bf(h_lds[2 * i][w * 16 + lane],
                       h_lds[2 * i + 1][w * 16 + lane]);
    *reinterpret_cast<short8v*>(
        hp + (((long long)(b * 256 + jt * 4 + w)) * 64 + q * 16 + lane) * 8) = o.v;
  }
}

// ---------------- gat_attn: identical to R20 (control) -----------------------
__global__ __launch_bounds__(512, 4) void gat_attn(const unsigned int* __restrict__ mask32,
                                                   const short* __restrict__ hp,
                                                   const float* __restrict__ e1g,
                                                   const float* __restrict__ f1g,
                                                   const float* __restrict__ e2g,
                                                   const float* __restrict__ f2g,
                                                   float* __restrict__ out) {
  const int b = blockIdx.y;
  const int i0 = blockIdx.x * 32;
  const int t = threadIdx.x;
  const int w = t >> 6, lane = t & 63;
  const int kg = lane >> 4, rl = lane & 15;

  __shared__ float red[8][1024];      // 32 KB; head overlaid with staging
  __shared__ float ps[8][16];
  __shared__ uint2 lut[16];

  unsigned int* mask_lds = reinterpret_cast<unsigned int*>(&red[0][0]);  // [32][65]
  float* e2_lds = &red[0][0] + 2080;                                     // 2048 floats
  float* f2_lds = &red[0][0] + 4128;                                     // 2048 floats

  if (t < 16) {
    const unsigned v = t;
    lut[t].x = ((v & 1u) ? 0xFFFFu : 0u) | ((v & 2u) ? 0xFFFF0000u : 0u);
    lut[t].y = ((v & 4u) ? 0xFFFFu : 0u) | ((v & 8u) ? 0xFFFF0000u : 0u);
  }
  // ---- stage 32 mask rows (coalesced uint4, scatter to [row][65]) ----
  {
    const uint4 mv = reinterpret_cast<const uint4*>(mask32 + i0 * 64)[t];
    const int row = t >> 4, col = (t & 15) * 4;
    mask_lds[row * 65 + col + 0] = mv.x;
    mask_lds[row * 65 + col + 1] = mv.y;
    mask_lds[row * 65 + col + 2] = mv.z;
    mask_lds[row * 65 + col + 3] = mv.w;
  }
  // ---- stage E2/F2 rows (2048 floats each, coalesced) ----
  {
    const float4 ev = reinterpret_cast<const float4*>(e2g + b * N_NODES)[t];
    const float4 fv = reinterpret_cast<const float4*>(f2g + b * N_NODES)[t];
    *reinterpret_cast<float4*>(&e2_lds[t * 4]) = ev;
    *reinterpret_cast<float4*>(&f2_lds[t * 4]) = fv;
  }
  __syncthreads();

  const float E11 = e1g[b * N_NODES + i0 + rl];
  const float F11 = f1g[b * N_NODES + i0 + rl];
  const float E12 = e1g[b * N_NODES + i0 + 16 + rl];
  const float F12 = f1g[b * N_NODES + i0 + 16 + rl];
  const short8v* hpB = reinterpret_cast<const short8v*>(hp) + (long long)b * 16384;

  f32x4 a10 = {0.f, 0.f, 0.f, 0.f}, a11 = {0.f, 0.f, 0.f, 0.f};
  f32x4 a12 = {0.f, 0.f, 0.f, 0.f}, a13 = {0.f, 0.f, 0.f, 0.f};
  f32x4 a20 = {0.f, 0.f, 0.f, 0.f}, a21 = {0.f, 0.f, 0.f, 0.f};
  f32x4 a22 = {0.f, 0.f, 0.f, 0.f}, a23 = {0.f, 0.f, 0.f, 0.f};
  f32x4 aS1 = {0.f, 0.f, 0.f, 0.f}, aS2 = {0.f, 0.f, 0.f, 0.f};
  union u8s { short8v v; unsigned u[4]; };
  u8s ones;
  #pragma unroll
  for (int i = 0; i < 4; ++i) ones.u[i] = 0x3F803F80u;

  // ---- prologue: prefetch iter 0's B-fragments ----
  const short8v* hp0 = hpB + w * 256;
  short8v nb0 = hp0[0 * 64 + lane];
  short8v nb1 = hp0[1 * 64 + lane];
  short8v nb2 = hp0[2 * 64 + lane];
  short8v nb3 = hp0[3 * 64 + lane];

  #pragma unroll
  for (int k = 0; k < 8; ++k) {
    const int jt = w + 8 * k;
    const short8v b0 = nb0, b1 = nb1, b2 = nb2, b3 = nb3;
    if (k < 7) {                       // prefetch next iter's fragments
      const short8v* hn = hpB + (jt + 8) * 256;
      nb0 = hn[0 * 64 + lane];
      nb1 = hn[1 * 64 + lane];
      nb2 = hn[2 * 64 + lane];
      nb3 = hn[3 * 64 + lane];
    }
    const float4 ea = *reinterpret_cast<const float4*>(&e2_lds[jt * 32 + kg * 8]);
    const float4 eb = *reinterpret_cast<const float4*>(&e2_lds[jt * 32 + kg * 8 + 4]);
    const float4 fa = *reinterpret_cast<const float4*>(&f2_lds[jt * 32 + kg * 8]);
    const float4 fb = *reinterpret_cast<const float4*>(&f2_lds[jt * 32 + kg * 8 + 4]);
    const unsigned int m1 = (mask_lds[rl * 65 + jt] >> (kg * 8)) & 0xFFu;
    const unsigned int m2 = (mask_lds[(16 + rl) * 65 + jt] >> (kg * 8)) & 0xFFu;
    const uint2 k10 = lut[m1 & 15u], k11 = lut[m1 >> 4];
    const uint2 k20 = lut[m2 & 15u], k21 = lut[m2 >> 4];
    const float e2e[8] = {ea.x, ea.y, ea.z, ea.w, eb.x, eb.y, eb.z, eb.w};
    const float f2e[8] = {fa.x, fa.y, fa.z, fa.w, fb.x, fb.y, fb.z, fb.w};
    float p1[8], p2[8];
    #pragma unroll
    for (int e = 0; e < 8; e++) {
      p1[e] = fmaxf(E11 * e2e[e], F11 * f2e[e]);
      p2[e] = fmaxf(E12 * e2e[e], F12 * f2e[e]);
    }
    u8s af1, af2;
    af1.u[0] = pack2bf(p1[0], p1[1]) & k10.x;
    af1.u[1] = pack2bf(p1[2], p1[3]) & k10.y;
    af1.u[2] = pack2bf(p1[4], p1[5]) & k11.x;
    af1.u[3] = pack2bf(p1[6], p1[7]) & k11.y;
    af2.u[0] = pack2bf(p2[0], p2[1]) & k20.x;
    af2.u[1] = pack2bf(p2[2], p2[3]) & k20.y;
    af2.u[2] = pack2bf(p2[4], p2[5]) & k21.x;
    af2.u[3] = pack2bf(p2[6], p2[7]) & k21.y;
    a10 = __builtin_amdgcn_mfma_f32_16x16x32_bf16(af1.v, b0, a10, 0, 0, 0);
    a20 = __builtin_amdgcn_mfma_f32_16x16x32_bf16(af2.v, b0, a20, 0, 0, 0);
    a11 = __builtin_amdgcn_mfma_f32_16x16x32_bf16(af1.v, b1, a11, 0, 0, 0);
    a21 = __builtin_amdgcn_mfma_f32_16x16x32_bf16(af2.v, b1, a21, 0, 0, 0);
    a12 = __builtin_amdgcn_mfma_f32_16x16x32_bf16(af1.v, b2, a12, 0, 0, 0);
    a22 = __builtin_amdgcn_mfma_f32_16x16x32_bf16(af2.v, b2, a22, 0, 0, 0);
    a13 = __builtin_amdgcn_mfma_f32_16x16x32_bf16(af1.v, b3, a13, 0, 0, 0);
    a23 = __builtin_amdgcn_mfma_f32_16x16x32_bf16(af2.v, b3, a23, 0, 0, 0);
    aS1 = __builtin_amdgcn_mfma_f32_16x16x32_bf16(af1.v, ones.v, aS1, 0, 0, 0);
    aS2 = __builtin_amdgcn_mfma_f32_16x16x32_bf16(af2.v, ones.v, aS2, 0, 0, 0);
  }

  __syncthreads();   // staging no longer needed; red reuse safe

  // ---- phase 1: rows i0..i0+15 ----
  #pragma unroll
  for (int r = 0; r < 4; r++) {
    red[w][(kg * 4 + r) * 64 + 0 * 16 + rl] = a10[r];
    red[w][(kg * 4 + r) * 64 + 1 * 16 + rl] = a11[r];
    red[w][(kg * 4 + r) * 64 + 2 * 16 + rl] = a12[r];
    red[w][(kg * 4 + r) * 64 + 3 * 16 + rl] = a13[r];
  }
  if (rl == 0) {
    #pragma unroll
    for (int r = 0; r < 4; r++) ps[w][kg * 4 + r] = aS1[r];
  }
  __syncthreads();
  {
    const int row = t >> 5;
    const int c2 = (t & 31) * 2;
    float den = 0.f, v0 = 0.f, v1 = 0.f;
    #pragma unroll
    for (int s = 0; s < 8; ++s) {
      den += ps[s][row];
      const float* rp = &red[s][row * 64 + c2];
      v0 += rp[0]; v1 += rp[1];
    }
    const float inv = 1.0f / den;
    float2 ov;
    ov.x = elu_f(v0 * inv);
    ov.y = elu_f(v1 * inv);
    *reinterpret_cast<float2*>(
        out + ((long long)b * N_NODES + i0 + row) * FOUT + c2) = ov;
  }
  __syncthreads();

  // ---- phase 2: rows i0+16..i0+31 ----
  #pragma unroll
  for (int r = 0; r < 4; r++) {
    red[w][(kg * 4 + r) * 64 + 0 * 16 + rl] = a20[r];
    red[w][(kg * 4 + r) * 64 + 1 * 16 + rl] = a21[r];
    red[w][(kg * 4 + r) * 64 + 2 * 16 + rl] = a22[r];
    red[w][(kg * 4 + r) * 64 + 3 * 16 + rl] = a23[r];
  }
  if (rl == 0) {
    #pragma unroll
    for (int r = 0; r < 4; r++) ps[w][kg * 4 + r] = aS2[r];
  }
  __syncthreads();
  {
    const int row = t >> 5;
    const int c2 = (t & 31) * 2;
    float den = 0.f, v0 = 0.f, v1 = 0.f;
    #pragma unroll
    for (int s = 0; s < 8; ++s) {
      den += ps[s][row];
      const float* rp = &red[s][row * 64 + c2];
      v0 += rp[0]; v1 += rp[1];
    }
    const float inv = 1.0f / den;
    float2 ov;
    ov.x = elu_f(v0 * inv);
    ov.y = elu_f(v1 * inv);
    *reinterpret_cast<float2*>(
        out + ((long long)b * N_NODES + i0 + 16 + row) * FOUT + c2) = ov;
  }
}

extern "C" void kernel_launch(void* const* d_in, const int* in_sizes, int n_in,
                              void* d_out, int out_size, void* d_ws, size_t ws_size,
                              hipStream_t stream) {
  const float* x   = (const float*)d_in[0];
  const int*   adj = (const int*)d_in[1];
  const float* W   = (const float*)d_in[2];
  const float* a   = (const float*)d_in[3];
  float* out = (float*)d_out;

  short* hp = (short*)d_ws;                                        // 2 MB
  float* e1 = (float*)(hp + (long long)BS * N_NODES * FOUT);       // 64 KB each
  float* f1 = e1 + BS * N_NODES;
  float* e2 = f1 + BS * N_NODES;
  float* f2 = e2 + BS * N_NODES;
  unsigned int* mask32 = (unsigned int*)(f2 + BS * N_NODES);       // 512 KB

  gat_prep<<<2048, 256, 0, stream>>>(x, adj, W, a, hp, e1, f1, e2, f2, mask32);
  gat_attn<<<dim3(N_NODES / 32, BS), 512, 0, stream>>>(mask32, hp, e1, f1, e2, f2, out);
}

// Round 22
// 27.497 us; speedup vs baseline: 1.0492x; 1.0492x over previous
//
#include <hip/hip_runtime.h>
#include <hip/hip_bf16.h>
#include <math.h>

#define N_NODES 2048
#define FIN 128
#define FOUT 64
#define BS 8
#define ALPHA 0.2f
#define LOG2E 1.4426950408889634f

typedef __attribute__((ext_vector_type(8))) short short8v;
typedef __attribute__((ext_vector_type(4))) float f32x4;

__device__ __forceinline__ unsigned int pack2bf(float a, float b) {
  __hip_bfloat162 t = __float22bfloat162_rn(make_float2(a, b));
  unsigned int r;
  __builtin_memcpy(&r, &t, 4);
  return r;
}
// hi/lo bf16 split of a float pair via packed cvt (RNE)
__device__ __forceinline__ void split2(float f0, float f1, unsigned &hi, unsigned &lo) {
  hi = pack2bf(f0, f1);
  const float h0 = __uint_as_float(hi << 16);
  const float h1 = __uint_as_float(hi & 0xFFFF0000u);
  lo = pack2bf(f0 - h0, f1 - h1);
}
__device__ __forceinline__ float elu_f(float v) {
  return v > 0.f ? v : expm1f(v);
}

// ---------------- gat_prep: MFMA h + exp-factor tables + hp/mask pack ---------
// 1024 blocks x 256 threads (4 waves). W hi/lo fragments computed inline per
// wave (W is 32 KB, L2-hot; saves the separate w_pack dispatch).
__global__ __launch_bounds__(256, 4) void gat_prep(const float* __restrict__ x,
                                                   const int* __restrict__ adj,
                                                   const float* __restrict__ W,
                                                   const float* __restrict__ a,
                                                   short* __restrict__ hp,
                                                   float* __restrict__ e1g,
                                                   float* __restrict__ f1g,
                                                   float* __restrict__ e2g,
                                                   float* __restrict__ f2g,
                                                   unsigned int* __restrict__ mask32) {
  const int bx = blockIdx.x;            // 0..1023
  const int b = bx >> 7;
  const int t16 = bx & 127;
  const int i0 = t16 * 16;
  const int t = threadIdx.x;
  const int w = t >> 6, lane = t & 63;
  const int kg = lane >> 4, rl = lane & 15;

  __shared__ float x_lds[16][132];           // 8.4 KB
  __shared__ float h_lds[16][68];            // 4.4 KB
  __shared__ unsigned char nib[2][512];      // 1 KB

  // ---- adj: 4 coalesced int4 loads/wave; row (w>>1), half (w&1) ----
  {
    const int row2 = w >> 1;
    const int half = w & 1;
    const int4* ar = reinterpret_cast<const int4*>(
        adj + (long long)(2 * bx + row2) * N_NODES + half * 1024);
    #pragma unroll
    for (int c = 0; c < 4; ++c) {
      const int4 v = ar[c * 64 + lane];
      const unsigned n = (v.x > 0 ? 1u : 0u) | (v.y > 0 ? 2u : 0u) |
                         (v.z > 0 ? 4u : 0u) | (v.w > 0 ? 8u : 0u);
      nib[row2][half * 256 + c * 64 + lane] = (unsigned char)n;
    }
  }

  // ---- coop x stage (coalesced) ----
  {
    const float* xrow = x + ((long long)b * N_NODES + i0 + (t >> 4)) * FIN + (t & 15) * 8;
    const float4 xa = *reinterpret_cast<const float4*>(xrow);
    const float4 xb = *reinterpret_cast<const float4*>(xrow + 4);
    *reinterpret_cast<float4*>(&x_lds[t >> 4][(t & 15) * 8]) = xa;
    *reinterpret_cast<float4*>(&x_lds[t >> 4][(t & 15) * 8 + 4]) = xb;
  }

  // ---- W fragments (hi/lo) inline for this wave's ct = w ----
  union u8s { short8v v; unsigned u[4]; };
  u8s bh[4], bl[4];
  #pragma unroll
  for (int ks = 0; ks < 4; ++ks) {
    #pragma unroll
    for (int pe = 0; pe < 4; ++pe) {
      const float w0 = W[(ks * 32 + kg * 8 + 2 * pe) * FOUT + w * 16 + rl];
      const float w1 = W[(ks * 32 + kg * 8 + 2 * pe + 1) * FOUT + w * 16 + rl];
      split2(w0, w1, bh[ks].u[pe], bl[ks].u[pe]);
    }
  }

  __syncthreads();   // x_lds + nib ready

  // ---- h tile via 3-term MFMA; x from LDS ----
  f32x4 ahh = {0.f, 0.f, 0.f, 0.f};
  f32x4 ahl = {0.f, 0.f, 0.f, 0.f};
  f32x4 alh = {0.f, 0.f, 0.f, 0.f};
  #pragma unroll
  for (int ks = 0; ks < 4; ++ks) {
    const float4 xa = *reinterpret_cast<const float4*>(&x_lds[rl][ks * 32 + kg * 8]);
    const float4 xb = *reinterpret_cast<const float4*>(&x_lds[rl][ks * 32 + kg * 8 + 4]);
    const float xf[8] = {xa.x, xa.y, xa.z, xa.w, xb.x, xb.y, xb.z, xb.w};
    u8s xh, xl;
    #pragma unroll
    for (int pe = 0; pe < 4; ++pe)
      split2(xf[2 * pe], xf[2 * pe + 1], xh.u[pe], xl.u[pe]);
    ahh = __builtin_amdgcn_mfma_f32_16x16x32_bf16(xh.v, bh[ks].v, ahh, 0, 0, 0);
    ahl = __builtin_amdgcn_mfma_f32_16x16x32_bf16(xh.v, bl[ks].v, ahl, 0, 0, 0);
    alh = __builtin_amdgcn_mfma_f32_16x16x32_bf16(xl.v, bh[ks].v, alh, 0, 0, 0);
  }
  const f32x4 acc = (ahh + ahl) + alh;
  #pragma unroll
  for (int r = 0; r < 4; ++r)
    h_lds[kg * 4 + r][w * 16 + rl] = acc[r];

  // ---- mask word assembly: threads 0..127 ----
  if (t < 128) {
    const int row2 = t >> 6, wd = t & 63;
    uint2 bytes;
    __builtin_memcpy(&bytes, &nib[row2][wd * 8], 8);
    const unsigned x0 = bytes.x, x1 = bytes.y;
    const unsigned lo16 = (x0 & 0xFu) | ((x0 >> 4) & 0xF0u) |
                          ((x0 >> 8) & 0xF00u) | ((x0 >> 12) & 0xF000u);
    const unsigned hi16 = (x1 & 0xFu) | ((x1 >> 4) & 0xF0u) |
                          ((x1 >> 8) & 0xF00u) | ((x1 >> 12) & 0xF000u);
    mask32[(2 * bx + row2) * 64 + wd] = lo16 | (hi16 << 16);
  }

  __syncthreads();   // h_lds ready

  // ---- s1/s2 reductions -> exp-factor tables ----
  {
    const float a1v = a[lane], a2v = a[FOUT + lane];
    #pragma unroll
    for (int rr = 0; rr < 4; ++rr) {
      const float hv = h_lds[4 * w + rr][lane];
      float p = hv * a1v, q = hv * a2v;
      #pragma unroll
      for (int off = 32; off > 0; off >>= 1) {
        p += __shfl_xor(p, off);
        q += __shfl_xor(q, off);
      }
      if (lane == 0) {
        const long long idx = (long long)b * N_NODES + i0 + 4 * w + rr;
        const float pl = p * LOG2E, ql = q * LOG2E;
        e1g[idx] = __builtin_amdgcn_exp2f(pl);
        f1g[idx] = __builtin_amdgcn_exp2f(pl * ALPHA);
        e2g[idx] = __builtin_amdgcn_exp2f(ql);
        f2g[idx] = __builtin_amdgcn_exp2f(ql * ALPHA);
      }
    }
  }

  // ---- hp pack ----
  if (lane < 32) {
    const int jt = t16 >> 1, kh = t16 & 1;
    const int kgl = lane >> 4, col = lane & 15;
    u8s o;
    #pragma unroll
    for (int i = 0; i < 4; ++i)
      o.u[i] = pack2bf(h_lds[kgl * 8 + 2 * i][w * 16 + col],
                       h_lds[kgl * 8 + 2 * i + 1][w * 16 + col]);
    *reinterpret_cast<short8v*>(
        hp + (((long long)(b * 256 + jt * 4 + w)) * 64 + (kh * 2 + kgl) * 16 + col) * 8) = o.v;
  }
}

// ---------------- gat_attn: factorized p, LDS tables, 2-deep hp prefetch ------
// Grid (64 i-tiles of 32 rows, 8 b), 512 threads = 8 j-stripe waves.
// B-fragments for iter k+1 prefetched into regs during iter k's compute.
__global__ __launch_bounds__(512, 4) void gat_attn(const unsigned int* __restrict__ mask32,
                                                   const short* __restrict__ hp,
                                                   const float* __restrict__ e1g,
                                                   const float* __restrict__ f1g,
                                                   const float* __restrict__ e2g,
                                                   const float* __restrict__ f2g,
                                                   float* __restrict__ out) {
  const int b = blockIdx.y;
  const int i0 = blockIdx.x * 32;
  const int t = threadIdx.x;
  const int w = t >> 6, lane = t & 63;
  const int kg = lane >> 4, rl = lane & 15;

  __shared__ float red[8][1024];      // 32 KB; head overlaid with staging
  __shared__ float ps[8][16];
  __shared__ uint2 lut[16];

  unsigned int* mask_lds = reinterpret_cast<unsigned int*>(&red[0][0]);  // [32][65]
  float* e2_lds = &red[0][0] + 2080;                                     // 2048 floats
  float* f2_lds = &red[0][0] + 4128;                                     // 2048 floats

  if (t < 16) {
    const unsigned v = t;
    lut[t].x = ((v & 1u) ? 0xFFFFu : 0u) | ((v & 2u) ? 0xFFFF0000u : 0u);
    lut[t].y = ((v & 4u) ? 0xFFFFu : 0u) | ((v & 8u) ? 0xFFFF0000u : 0u);
  }
  // ---- stage 32 mask rows (coalesced uint4, scatter to [row][65]) ----
  {
    const uint4 mv = reinterpret_cast<const uint4*>(mask32 + i0 * 64)[t];
    const int row = t >> 4, col = (t & 15) * 4;
    mask_lds[row * 65 + col + 0] = mv.x;
    mask_lds[row * 65 + col + 1] = mv.y;
    mask_lds[row * 65 + col + 2] = mv.z;
    mask_lds[row * 65 + col + 3] = mv.w;
  }
  // ---- stage E2/F2 rows (2048 floats each, coalesced) ----
  {
    const float4 ev = reinterpret_cast<const float4*>(e2g + b * N_NODES)[t];
    const float4 fv = reinterpret_cast<const float4*>(f2g + b * N_NODES)[t];
    *reinterpret_cast<float4*>(&e2_lds[t * 4]) = ev;
    *reinterpret_cast<float4*>(&f2_lds[t * 4]) = fv;
  }
  __syncthreads();

  const float E11 = e1g[b * N_NODES + i0 + rl];
  const float F11 = f1g[b * N_NODES + i0 + rl];
  const float E12 = e1g[b * N_NODES + i0 + 16 + rl];
  const float F12 = f1g[b * N_NODES + i0 + 16 + rl];
  const short8v* hpB = reinterpret_cast<const short8v*>(hp) + (long long)b * 16384;

  f32x4 a10 = {0.f, 0.f, 0.f, 0.f}, a11 = {0.f, 0.f, 0.f, 0.f};
  f32x4 a12 = {0.f, 0.f, 0.f, 0.f}, a13 = {0.f, 0.f, 0.f, 0.f};
  f32x4 a20 = {0.f, 0.f, 0.f, 0.f}, a21 = {0.f, 0.f, 0.f, 0.f};
  f32x4 a22 = {0.f, 0.f, 0.f, 0.f}, a23 = {0.f, 0.f, 0.f, 0.f};
  f32x4 aS1 = {0.f, 0.f, 0.f, 0.f}, aS2 = {0.f, 0.f, 0.f, 0.f};
  union u8s { short8v v; unsigned u[4]; };
  u8s ones;
  #pragma unroll
  for (int i = 0; i < 4; ++i) ones.u[i] = 0x3F803F80u;

  // ---- prologue: prefetch iter 0's B-fragments ----
  const short8v* hp0 = hpB + w * 256;
  short8v nb0 = hp0[0 * 64 + lane];
  short8v nb1 = hp0[1 * 64 + lane];
  short8v nb2 = hp0[2 * 64 + lane];
  short8v nb3 = hp0[3 * 64 + lane];

  #pragma unroll
  for (int k = 0; k < 8; ++k) {
    const int jt = w + 8 * k;
    const short8v b0 = nb0, b1 = nb1, b2 = nb2, b3 = nb3;
    if (k < 7) {                       // prefetch next iter's fragments
      const short8v* hn = hpB + (jt + 8) * 256;
      nb0 = hn[0 * 64 + lane];
      nb1 = hn[1 * 64 + lane];
      nb2 = hn[2 * 64 + lane];
      nb3 = hn[3 * 64 + lane];
    }
    const float4 ea = *reinterpret_cast<const float4*>(&e2_lds[jt * 32 + kg * 8]);
    const float4 eb = *reinterpret_cast<const float4*>(&e2_lds[jt * 32 + kg * 8 + 4]);
    const float4 fa = *reinterpret_cast<const float4*>(&f2_lds[jt * 32 + kg * 8]);
    const float4 fb = *reinterpret_cast<const float4*>(&f2_lds[jt * 32 + kg * 8 + 4]);
    const unsigned int m1 = (mask_lds[rl * 65 + jt] >> (kg * 8)) & 0xFFu;
    const unsigned int m2 = (mask_lds[(16 + rl) * 65 + jt] >> (kg * 8)) & 0xFFu;
    const uint2 k10 = lut[m1 & 15u], k11 = lut[m1 >> 4];
    const uint2 k20 = lut[m2 & 15u], k21 = lut[m2 >> 4];
    const float e2e[8] = {ea.x, ea.y, ea.z, ea.w, eb.x, eb.y, eb.z, eb.w};
    const float f2e[8] = {fa.x, fa.y, fa.z, fa.w, fb.x, fb.y, fb.z, fb.w};
    float p1[8], p2[8];
    #pragma unroll
    for (int e = 0; e < 8; e++) {
      p1[e] = fmaxf(E11 * e2e[e], F11 * f2e[e]);
      p2[e] = fmaxf(E12 * e2e[e], F12 * f2e[e]);
    }
    u8s af1, af2;
    af1.u[0] = pack2bf(p1[0], p1[1]) & k10.x;
    af1.u[1] = pack2bf(p1[2], p1[3]) & k10.y;
    af1.u[2] = pack2bf(p1[4], p1[5]) & k11.x;
    af1.u[3] = pack2bf(p1[6], p1[7]) & k11.y;
    af2.u[0] = pack2bf(p2[0], p2[1]) & k20.x;
    af2.u[1] = pack2bf(p2[2], p2[3]) & k20.y;
    af2.u[2] = pack2bf(p2[4], p2[5]) & k21.x;
    af2.u[3] = pack2bf(p2[6], p2[7]) & k21.y;
    a10 = __builtin_amdgcn_mfma_f32_16x16x32_bf16(af1.v, b0, a10, 0, 0, 0);
    a20 = __builtin_amdgcn_mfma_f32_16x16x32_bf16(af2.v, b0, a20, 0, 0, 0);
    a11 = __builtin_amdgcn_mfma_f32_16x16x32_bf16(af1.v, b1, a11, 0, 0, 0);
    a21 = __builtin_amdgcn_mfma_f32_16x16x32_bf16(af2.v, b1, a21, 0, 0, 0);
    a12 = __builtin_amdgcn_mfma_f32_16x16x32_bf16(af1.v, b2, a12, 0, 0, 0);
    a22 = __builtin_amdgcn_mfma_f32_16x16x32_bf16(af2.v, b2, a22, 0, 0, 0);
    a13 = __builtin_amdgcn_mfma_f32_16x16x32_bf16(af1.v, b3, a13, 0, 0, 0);
    a23 = __builtin_amdgcn_mfma_f32_16x16x32_bf16(af2.v, b3, a23, 0, 0, 0);
    aS1 = __builtin_amdgcn_mfma_f32_16x16x32_bf16(af1.v, ones.v, aS1, 0, 0, 0);
    aS2 = __builtin_amdgcn_mfma_f32_16x16x32_bf16(af2.v, ones.v, aS2, 0, 0, 0);
  }

  __syncthreads();   // staging no longer needed; red reuse safe

  // ---- phase 1: rows i0..i0+15 ----
  #pragma unroll
  for (int r = 0; r < 4; r++) {
    red[w][(kg * 4 + r) * 64 + 0 * 16 + rl] = a10[r];
    red[w][(kg * 4 + r) * 64 + 1 * 16 + rl] = a11[r];
    red[w][(kg * 4 + r) * 64 + 2 * 16 + rl] = a12[r];
    red[w][(kg * 4 + r) * 64 + 3 * 16 + rl] = a13[r];
  }
  if (rl == 0) {
    #pragma unroll
    for (int r = 0; r < 4; r++) ps[w][kg * 4 + r] = aS1[r];
  }
  __syncthreads();
  {
    const int row = t >> 5;
    const int c2 = (t & 31) * 2;
    float den = 0.f, v0 = 0.f, v1 = 0.f;
    #pragma unroll
    for (int s = 0; s < 8; ++s) {
      den += ps[s][row];
      const float* rp = &red[s][row * 64 + c2];
      v0 += rp[0]; v1 += rp[1];
    }
    const float inv = 1.0f / den;
    float2 ov;
    ov.x = elu_f(v0 * inv);
    ov.y = elu_f(v1 * inv);
    *reinterpret_cast<float2*>(
        out + ((long long)b * N_NODES + i0 + row) * FOUT + c2) = ov;
  }
  __syncthreads();

  // ---- phase 2: rows i0+16..i0+31 ----
  #pragma unroll
  for (int r = 0; r < 4; r++) {
    red[w][(kg * 4 + r) * 64 + 0 * 16 + rl] = a20[r];
    red[w][(kg * 4 + r) * 64 + 1 * 16 + rl] = a21[r];
    red[w][(kg * 4 + r) * 64 + 2 * 16 + rl] = a22[r];
    red[w][(kg * 4 + r) * 64 + 3 * 16 + rl] = a23[r];
  }
  if (rl == 0) {
    #pragma unroll
    for (int r = 0; r < 4; r++) ps[w][kg * 4 + r] = aS2[r];
  }
  __syncthreads();
  {
    const int row = t >> 5;
    const int c2 = (t & 31) * 2;
    float den = 0.f, v0 = 0.f, v1 = 0.f;
    #pragma unroll
    for (int s = 0; s < 8; ++s) {
      den += ps[s][row];
      const float* rp = &red[s][row * 64 + c2];
      v0 += rp[0]; v1 += rp[1];
    }
    const float inv = 1.0f / den;
    float2 ov;
    ov.x = elu_f(v0 * inv);
    ov.y = elu_f(v1 * inv);
    *reinterpret_cast<float2*>(
        out + ((long long)b * N_NODES + i0 + 16 + row) * FOUT + c2) = ov;
  }
}

extern "C" void kernel_launch(void* const* d_in, const int* in_sizes, int n_in,
                              void* d_out, int out_size, void* d_ws, size_t ws_size,
                              hipStream_t stream) {
  const float* x   = (const float*)d_in[0];
  const int*   adj = (const int*)d_in[1];
  const float* W   = (const float*)d_in[2];
  const float* a   = (const float*)d_in[3];
  float* out = (float*)d_out;

  short* hp = (short*)d_ws;                                        // 2 MB
  float* e1 = (float*)(hp + (long long)BS * N_NODES * FOUT);       // 64 KB each
  float* f1 = e1 + BS * N_NODES;
  float* e2 = f1 + BS * N_NODES;
  float* f2 = e2 + BS * N_NODES;
  unsigned int* mask32 = (unsigned int*)(f2 + BS * N_NODES);       // 512 KB

  gat_prep<<<1024, 256, 0, stream>>>(x, adj, W, a, hp, e1, f1, e2, f2, mask32);
  gat_attn<<<dim3(N_NODES / 32, BS), 512, 0, stream>>>(mask32, hp, e1, f1, e2, f2, out);
}